// Round 4
// baseline (484.931 us; speedup 1.0000x reference)
//
#include <hip/hip_runtime.h>

// Patch2Im col2im (k=7, stride=3), gather, phase-decomposed + 4-wide chunks.
// wp = 3q + r contributions:
//   r=0: j=0@pw=q, j=3@pw=q-1, j=6@pw=q-2
//   r=1: j=1@pw=q, j=4@pw=q-1
//   r=2: j=2@pw=q, j=5@pw=q-1
// One thread owns (bc, h, tt) with t = 4*tt + e, e=0..3 (q = t+1), producing
// 12 outputs w = 12*tt .. 12*tt+11. Per contributing ph row it issues 7
// 16-byte loads (planes j=0..6 at col offsets t0+1 / t0 / t0-1) -> wave-level
// contiguous 1KB transactions. Edge terms (t=0 j6, t=84 j0) are memory-safe
// over-reads zeroed by float masks.

constexpr int K   = 7;
constexpr int S   = 3;
constexpr int NH  = 85;
constexpr int NW  = 85;
constexpr int OH  = 253;
constexpr int OW  = 253;
constexpr int PAD = 3;
constexpr int PLANE  = NH * NW;   // 7225
constexpr int CHUNKS = 22;        // ceil(85/4) t-chunks per row

__device__ __forceinline__ void ld4(float* dst, const float* p) {
    __builtin_memcpy(dst, p, 16);   // 4B-aligned 16B load (dwordx4 on gfx950)
}

__global__ __launch_bounds__(256) void patch2im_kernel(
    const float* __restrict__ x, float* __restrict__ out, int total)
{
    int idx = blockIdx.x * 256 + threadIdx.x;
    if (idx >= total) return;

    int tt = idx % CHUNKS;
    int r2 = idx / CHUNKS;
    int h  = r2 % OH;
    int bc = r2 / OH;

    int t0 = 4 * tt;                 // chunk covers t = t0 .. t0+3
    int hp = h + PAD;                // [3, 256)

    int ph_min = (hp >= K) ? (hp - (K - 1) + (S - 1)) / S : 0;   // (hp-4)/3
    int ph_max = hp / S;
    if (ph_max > NH - 1) ph_max = NH - 1;
    int nh = ph_max - ph_min + 1;    // 2 or 3

    const float* base = x + (size_t)bc * (K * K * PLANE);

    float m6 = (tt == 0)          ? 0.f : 1.f;  // kill j6 term at t=0
    float m0 = (tt == CHUNKS - 1) ? 0.f : 1.f;  // kill j0 term at t=84

    float o0[4] = {0.f, 0.f, 0.f, 0.f};
    float o1[4] = {0.f, 0.f, 0.f, 0.f};
    float o2[4] = {0.f, 0.f, 0.f, 0.f};

    for (int ph = ph_min; ph <= ph_max; ++ph) {
        int i = hp - S * ph;                               // [0, K)
        const float* pb = base + (i * K) * PLANE + ph * NW;

        float a0[4], a1[4], a2[4], a3[4], a4[4], a5[4], a6[4];
        ld4(a0, pb + 0 * PLANE + t0 + 1);   // j=0 @ pw = t+1
        ld4(a1, pb + 1 * PLANE + t0 + 1);   // j=1 @ pw = t+1
        ld4(a2, pb + 2 * PLANE + t0 + 1);   // j=2 @ pw = t+1
        ld4(a3, pb + 3 * PLANE + t0);       // j=3 @ pw = t
        ld4(a4, pb + 4 * PLANE + t0);       // j=4 @ pw = t
        ld4(a5, pb + 5 * PLANE + t0);       // j=5 @ pw = t
        ld4(a6, pb + 6 * PLANE + t0 - 1);   // j=6 @ pw = t-1

        a6[0] *= m6;
        a0[0] *= m0;

        #pragma unroll
        for (int e = 0; e < 4; ++e) {
            o0[e] += a0[e] + a3[e] + a6[e];
            o1[e] += a1[e] + a4[e];
            o2[e] += a2[e] + a5[e];
        }
    }

    // denominators: nh * nw, nw = 3 for interior r=0, else 2
    float inv2 = (nh == 3) ? (1.f / 6.f) : (1.f / 4.f);   // 1/(2*nh)
    float inv3 = (nh == 3) ? (1.f / 9.f) : (1.f / 6.f);   // 1/(3*nh)

    float* orow = out + ((size_t)bc * OH + h) * OW + 3 * t0;

    #pragma unroll
    for (int e = 0; e < 4; ++e) {
        int t = t0 + e;
        if (t > NW - 1) break;                 // only chunk 21 hits this
        bool edge = (t == 0) | (t == NW - 1);
        orow[3 * e] = o0[e] * (edge ? inv2 : inv3);
        if (t < NW - 1) {                      // w = 253,254 don't exist
            orow[3 * e + 1] = o1[e] * inv2;
            orow[3 * e + 2] = o2[e] * inv2;
        }
    }
}

extern "C" void kernel_launch(void* const* d_in, const int* in_sizes, int n_in,
                              void* d_out, int out_size, void* d_ws, size_t ws_size,
                              hipStream_t stream) {
    const float* x = (const float*)d_in[0];
    float* out = (float*)d_out;

    int total = 256 * OH * CHUNKS;            // 1,424,896 threads
    int blocks = (total + 255) / 256;
    patch2im_kernel<<<blocks, 256, 0, stream>>>(x, out, total);
}